// Round 9
// baseline (306.533 us; speedup 1.0000x reference)
//
#include <hip/hip_runtime.h>
#include <hip/hip_bf16.h>
#include <cstdint>
#include <cstddef>

typedef short bf16x8 __attribute__((ext_vector_type(8)));
typedef float f32x4 __attribute__((ext_vector_type(4)));

namespace {
constexpr int kB = 2048;
constexpr int kN = 65536;
constexpr int kF = 128;
constexpr int kLabels = 10;
constexpr int kIMax = 0x7fffffff;

constexpr int BM = 128;             // rows per WG
constexpr int BN = 256;             // cols per n-tile
constexpr int SLICE = 2048;         // cols per WG
constexpr int NTILES = SLICE / BN;  // 8
constexpr int NCH = 4;              // K chunks: 128/32, bf16 HI-ONLY ranking
constexpr int NCHT = NTILES * NCH;  // 32 chunks per WG
constexpr int NSUB = kN / 32;       // 2048 bins of 32 (strided) cols
// Ranking error: hi-only bf16 dot, sigma_d ~= 0.012. Margin 0.25 ~= 20 sigma;
// bin-capture proof needs >= 8 sigma. Rescore is exact fp32, so margin only
// affects how many bins get rescored (~0.6 extra per row at this width).
constexpr float kMargin = 0.25f;
}

#define TOP3_INSERT(dd, ii, D0, I0, D1, I1, D2, I2)                              \
  do {                                                                           \
    float _d = (dd); int _i = (ii);                                              \
    if (_d < (D0) || (_d == (D0) && _i < (I0))) {                                \
      (D2) = (D1); (I2) = (I1); (D1) = (D0); (I1) = (I0); (D0) = _d; (I0) = _i;  \
    } else if (_d < (D1) || (_d == (D1) && _i < (I1))) {                         \
      (D2) = (D1); (I2) = (I1); (D1) = _d; (I1) = _i;                            \
    } else if (_d < (D2) || (_d == (D2) && _i < (I2))) {                         \
      (D2) = _d; (I2) = _i;                                                      \
    }                                                                            \
  } while (0)

__device__ inline unsigned short f2bf(float a) {
  __hip_bfloat16 h = __float2bfloat16(a);
  return __builtin_bit_cast(unsigned short, h);
}

__device__ inline void gload_lds16(const void* g, void* l) {
  __builtin_amdgcn_global_load_lds(
      (const __attribute__((address_space(1))) void*)g,
      (__attribute__((address_space(3))) void*)l, 16, 0, 0);
}

// ---------- kernel 1: fused pack (bf16 hi only) + sumsq ----------
// One wave per entry. A pack = bf16(f*x), left = sum x^2.
// B pack = bf16(w), right = sum (f*w)^2. 256 B per row/col.
__global__ __launch_bounds__(256) void pack_sumsq_kernel(
    const float* __restrict__ x, const float* __restrict__ train,
    const float* __restrict__ features, unsigned short* __restrict__ Ap,
    unsigned short* __restrict__ Bp, float* __restrict__ left,
    float* __restrict__ right) {
  const int wid = (int)((blockIdx.x * 256 + threadIdx.x) >> 6);
  const int lane = threadIdx.x & 63;
  if (wid >= kB + kN) return;
  const float2 fv = reinterpret_cast<const float2*>(features)[lane];
  const float* src;
  unsigned short* dst;
  float pm0, pm1, sm0, sm1;
  if (wid < kB) {
    src = x + (size_t)wid * kF;
    dst = Ap + (size_t)wid * 128;
    pm0 = fv.x; pm1 = fv.y;   // pack f*x
    sm0 = 1.0f; sm1 = 1.0f;   // left = sum x^2
  } else {
    src = train + (size_t)(wid - kB) * kF;
    dst = Bp + (size_t)(wid - kB) * 128;
    pm0 = 1.0f; pm1 = 1.0f;   // pack raw w
    sm0 = fv.x; sm1 = fv.y;   // right = sum (f*w)^2
  }
  const float2 v = reinterpret_cast<const float2*>(src)[lane];
  const float pa = v.x * pm0, pb = v.y * pm1;
  const float sa = v.x * sm0, sb = v.y * sm1;
  const unsigned short ha = f2bf(pa), hb = f2bf(pb);
  reinterpret_cast<unsigned int*>(dst)[lane] = (unsigned int)ha | ((unsigned int)hb << 16);
  float s = sa * sa + sb * sb;
  #pragma unroll
  for (int m = 1; m <= 32; m <<= 1) s += __shfl_xor(s, m);
  if (lane == 0) {
    if (wid < kB) left[wid] = s;
    else right[wid - kB] = s;
  }
}

// ---------- kernel 2: hi-only bf16 MFMA distance estimate + per-bin min -----
// grid (32 slices, 16 m-blocks), 256 threads (4 waves: 2m x 2n over 128x256).
// 80 KB LDS -> 2 WGs/CU; 3-deep rotation, counted vmcnt (12/6/0, 6 loads per
// stage), compiler-scheduled ds_read<->MFMA interleave. Structure = r8, with
// NCH 12 -> 4 (no lo terms).
__global__ __launch_bounds__(256, 2) void knn_main_kernel(
    const unsigned short* __restrict__ Ap, const unsigned short* __restrict__ Bp,
    const float* __restrict__ left, const float* __restrict__ right,
    float* __restrict__ minbuf) {
  __shared__ alignas(16) unsigned short lsA[3][BM * 32];  // 8 KB x3
  __shared__ alignas(16) unsigned short lsB[3][BN * 32];  // 16 KB x3
  __shared__ alignas(16) float lsR[SLICE];                // 8 KB   => 80 KB total

  const int slice = blockIdx.x;
  const int mb = blockIdx.y;
  const int row0 = mb * BM;
  const int col0 = slice * SLICE;
  const int t = threadIdx.x;
  const int lane = t & 63;
  const int wm = (t >> 6) >> 1;  // 0..1
  const int wn = (t >> 6) & 1;   // 0..1

  // stage right-slice (2048 f32) into LDS
  #pragma unroll
  for (int i = 0; i < 2; ++i)
    reinterpret_cast<float4*>(lsR)[t + i * 256] =
        reinterpret_cast<const float4*>(right + col0)[t + i * 256];

  // left per lane-row
  float lrow[4][4];
  #pragma unroll
  for (int mf = 0; mf < 4; ++mf)
    #pragma unroll
    for (int rg = 0; rg < 4; ++rg)
      lrow[mf][rg] = left[row0 + wm * 64 + mf * 16 + (lane >> 4) * 4 + rg];

  // staging addresses: A instr i covers rows i*64 + t/4, B instr i covers
  // cols i*64 + t/4; slot p = t&3 source-XOR-swizzled, LDS linear [row][slot].
  // Pack stride now 256 B (128 bf16 hi).
  const int rr = t >> 2;
  const int p = t & 3;
  size_t gbaseA[2], gbaseB[4];
  int ldsoffA[2], ldsoffB[4];
  #pragma unroll
  for (int i = 0; i < 2; ++i) {
    const int r = i * 64 + rr;
    const int ps = p ^ ((r >> 1) & 3);
    gbaseA[i] = (size_t)(row0 + r) * 256 + (size_t)ps * 16;
    ldsoffA[i] = i * 4096 + t * 16;
  }
  #pragma unroll
  for (int i = 0; i < 4; ++i) {
    const int r = i * 64 + rr;
    const int ps = p ^ ((r >> 1) & 3);
    gbaseB[i] = (size_t)(col0 + r) * 256 + (size_t)ps * 16;
    ldsoffB[i] = i * 4096 + t * 16;
  }

  // fragment LDS byte offsets (swizzled reads, verified r2-r8)
  int offA[4], offB[8];
  #pragma unroll
  for (int mf = 0; mf < 4; ++mf) {
    const int rl = wm * 64 + mf * 16 + (lane & 15);
    offA[mf] = rl * 64 + (((lane >> 4) ^ ((rl >> 1) & 3)) * 16);
  }
  #pragma unroll
  for (int nf = 0; nf < 8; ++nf) {
    const int cl = wn * 128 + nf * 16 + (lane & 15);
    offB[nf] = cl * 64 + (((lane >> 4) ^ ((cl >> 1) & 3)) * 16);
  }

  const char* ApB = (const char*)Ap;
  const char* BpB = (const char*)Bp;

  auto stage = [&](int buf, int c, int nt) {
    // hi-only: chunk c covers k-window c*32 (byte offset c*64), identity map.
    char* lA = (char*)&lsA[buf][0];
    char* lB = (char*)&lsB[buf][0];
    #pragma unroll
    for (int i = 0; i < 2; ++i)
      gload_lds16(ApB + gbaseA[i] + (size_t)c * 64, lA + ldsoffA[i]);
    #pragma unroll
    for (int i = 0; i < 4; ++i)
      gload_lds16(BpB + gbaseB[i] + (size_t)nt * 65536 + (size_t)c * 64, lB + ldsoffB[i]);
  };

  // Drain once (protects lsR init), then start the pipeline.
  asm volatile("s_waitcnt vmcnt(0) lgkmcnt(0)" ::: "memory");
  __syncthreads();

  // prologue: prefetch chunks 0,1
  stage(0, 0, 0);
  stage(1, 1, 0);

  const bool bwriter = (lane & 3) == 0;

  int g = 0;  // global chunk index
  for (int nt = 0; nt < NTILES; ++nt) {
    f32x4 acc[4][8];
    #pragma unroll
    for (int mf = 0; mf < 4; ++mf)
      #pragma unroll
      for (int nf = 0; nf < 8; ++nf)
        acc[mf][nf] = (f32x4){0.f, 0.f, 0.f, 0.f};

    for (int c = 0; c < NCH; ++c, ++g) {
      if (g + 2 < NCHT)
        stage((g + 2) % 3, (g + 2) & 3, (g + 2) >> 2);
      // counted wait: chunk g ready iff <= 2 newer stages (6 loads each) out.
      if (g <= NCHT - 3)       asm volatile("s_waitcnt vmcnt(12)" ::: "memory");
      else if (g == NCHT - 2)  asm volatile("s_waitcnt vmcnt(6)" ::: "memory");
      else                     asm volatile("s_waitcnt vmcnt(0)" ::: "memory");
      __builtin_amdgcn_s_barrier();
      asm volatile("" ::: "memory");

      const char* lA = (const char*)&lsA[g % 3][0];
      const char* lB = (const char*)&lsB[g % 3][0];
      bf16x8 a[4], b[8];
      #pragma unroll
      for (int mf = 0; mf < 4; ++mf)
        a[mf] = *reinterpret_cast<const bf16x8*>(lA + offA[mf]);
      #pragma unroll
      for (int nf = 0; nf < 8; ++nf)
        b[nf] = *reinterpret_cast<const bf16x8*>(lB + offB[nf]);
      // compiler-scheduled lgkmcnt interleave (no pin; m97/m141 evidence)
      __builtin_amdgcn_s_setprio(1);
      #pragma unroll
      for (int mf = 0; mf < 4; ++mf)
        #pragma unroll
        for (int nf = 0; nf < 8; ++nf)
          acc[mf][nf] = __builtin_amdgcn_mfma_f32_16x16x32_bf16(
              a[mf], b[nf], acc[mf][nf], 0, 0, 0);
      __builtin_amdgcn_s_setprio(0);
      asm volatile("" ::: "memory");
      __builtin_amdgcn_s_barrier();   // reads of buf g done before its reuse
      asm volatile("" ::: "memory");
    }

    // epilogue: distance estimate + per-bin (32 strided cols) min.
    float rj[8];
    #pragma unroll
    for (int nf = 0; nf < 8; ++nf)
      rj[nf] = lsR[nt * 256 + wn * 128 + nf * 16 + (lane & 15)];
    const int binbase = slice * 64 + nt * 8 + wn * 4 + ((lane >> 2) & 3);
    #pragma unroll
    for (int mf = 0; mf < 4; ++mf) {
      #pragma unroll
      for (int rg = 0; rg < 4; ++rg) {
        const float l = lrow[mf][rg];
        float d[8];
        #pragma unroll
        for (int nf = 0; nf < 8; ++nf)
          d[nf] = sqrtf(l + rj[nf]) - 2.0f * acc[mf][nf][rg];
        d[0] = fminf(d[0], d[4]); d[1] = fminf(d[1], d[5]);
        d[2] = fminf(d[2], d[6]); d[3] = fminf(d[3], d[7]);
        d[0] = fminf(d[0], d[2]); d[1] = fminf(d[1], d[3]);
        float v = fminf(d[0], d[1]);
        v = fminf(v, __shfl_xor(v, 1));
        v = fminf(v, __shfl_xor(v, 2));
        if (bwriter) {
          const int row = row0 + wm * 64 + mf * 16 + (lane >> 4) * 4 + rg;
          minbuf[(size_t)row * NSUB + binbase] = v;
        }
      }
    }
  }
}

// ---------- kernel 3: select bins, exact fp32 rescore, outputs ----------
__global__ __launch_bounds__(256) void select_rescore_kernel(
    const float* __restrict__ x, const float* __restrict__ train,
    const float* __restrict__ features, const float* __restrict__ left,
    const float* __restrict__ right, const int* __restrict__ labels,
    const float* __restrict__ minbuf, float* __restrict__ out) {
  __shared__ float Xs[4][kF];
  const int t = threadIdx.x;
  if (t < 128) {
    const int rr = t >> 5, q = t & 31;
    float4 xv = reinterpret_cast<const float4*>(
        x + (size_t)(blockIdx.x * 4 + rr) * kF)[q];
    const float4 f = reinterpret_cast<const float4*>(features)[q];
    xv.x *= f.x; xv.y *= f.y; xv.z *= f.z; xv.w *= f.w;
    reinterpret_cast<float4*>(&Xs[rr][0])[q] = xv;
  }
  __syncthreads();
  const int wave = t >> 6, lane = t & 63;
  const int row = blockIdx.x * 4 + wave;
  const float lr = left[row];
  const float* mrow = minbuf + (size_t)row * NSUB;

  // pass 1: 3rd-smallest bin min
  float v0 = __builtin_inff(), v1 = v0, v2 = v0;
  #pragma unroll 4
  for (int i = 0; i < NSUB / 64; ++i) {
    const float m = mrow[i * 64 + lane];
    if (m < v0) { v2 = v1; v1 = v0; v0 = m; }
    else if (m < v1) { v2 = v1; v1 = m; }
    else if (m < v2) { v2 = m; }
  }
  #pragma unroll
  for (int msk = 1; msk <= 32; msk <<= 1) {
    const float e0 = __shfl_xor(v0, msk), e1 = __shfl_xor(v1, msk), e2 = __shfl_xor(v2, msk);
    if (e0 < v0) { v2 = v1; v1 = v0; v0 = e0; } else if (e0 < v1) { v2 = v1; v1 = e0; } else if (e0 < v2) v2 = e0;
    if (e1 < v0) { v2 = v1; v1 = v0; v0 = e1; } else if (e1 < v1) { v2 = v1; v1 = e1; } else if (e1 < v2) v2 = e1;
    if (e2 < v0) { v2 = v1; v1 = v0; v0 = e2; } else if (e2 < v1) { v2 = v1; v1 = e2; } else if (e2 < v2) v2 = e2;
  }
  const float tau = v2 + kMargin;

  // pass 2: exact fp32 rescore of selected bins.
  // bin sub -> cols { (sub>>2)*128 + nf*16 + (sub&3)*4 + g : nf 0..7, g 0..3 }
  float d0 = __builtin_inff(), d1 = d0, d2 = d0;
  int i0 = kIMax, i1 = kIMax, i2 = kIMax;
  for (int base = 0; base < NSUB; base += 64) {
    const float m = mrow[base + lane];
    unsigned long long msk = __ballot(m <= tau);
    while (msk) {
      const int bpos = __builtin_ctzll(msk);
      msk &= msk - 1;
      const int sub = base + bpos;
      if (lane < 32) {
        const int j = (sub >> 2) * 128 + (lane >> 2) * 16 + (sub & 3) * 4 + (lane & 3);
        const float4* wp = reinterpret_cast<const float4*>(train + (size_t)j * kF);
        float acc = 0.f;
        #pragma unroll 8
        for (int kq = 0; kq < 32; ++kq) {
          const float4 w4 = wp[kq];
          const float4 x4 = reinterpret_cast<const float4*>(&Xs[wave][0])[kq];
          acc = fmaf(x4.w, w4.w, fmaf(x4.z, w4.z, fmaf(x4.y, w4.y, fmaf(x4.x, w4.x, acc))));
        }
        const float d = sqrtf(lr + right[j]) - 2.0f * acc;
        TOP3_INSERT(d, j, d0, i0, d1, i1, d2, i2);
      }
    }
  }
  #pragma unroll
  for (int msk = 1; msk <= 32; msk <<= 1) {
    const float e0 = __shfl_xor(d0, msk), e1 = __shfl_xor(d1, msk), e2 = __shfl_xor(d2, msk);
    const int f0 = __shfl_xor(i0, msk), f1 = __shfl_xor(i1, msk), f2 = __shfl_xor(i2, msk);
    TOP3_INSERT(e0, f0, d0, i0, d1, i1, d2, i2);
    TOP3_INSERT(e1, f1, d0, i0, d1, i1, d2, i2);
    TOP3_INSERT(e2, f2, d0, i0, d1, i1, d2, i2);
  }
  if (lane == 0) {
    const int l0 = labels[i0], l1 = labels[i1], l2 = labels[i2];
    const int o = (l0 + l1 + l2) / 3;
    float* one_hot = out;
    float* values = out + (size_t)kB * kLabels;
    float* indices = values + (size_t)kB * 3;
    float* labs = indices + (size_t)kB * 3;
    #pragma unroll
    for (int c = 0; c < kLabels; ++c)
      one_hot[(size_t)row * kLabels + c] = (c == o) ? 1.0f : 0.0f;
    values[row * 3 + 0] = -d0; values[row * 3 + 1] = -d1; values[row * 3 + 2] = -d2;
    indices[row * 3 + 0] = (float)i0; indices[row * 3 + 1] = (float)i1; indices[row * 3 + 2] = (float)i2;
    labs[row * 3 + 0] = (float)l0; labs[row * 3 + 1] = (float)l1; labs[row * 3 + 2] = (float)l2;
  }
}

extern "C" void kernel_launch(void* const* d_in, const int* in_sizes, int n_in,
                              void* d_out, int out_size, void* d_ws, size_t ws_size,
                              hipStream_t stream) {
  const float* x = (const float*)d_in[0];
  const float* train = (const float*)d_in[1];
  const int* labels = (const int*)d_in[2];
  const float* features = (const float*)d_in[3];
  float* out = (float*)d_out;

  char* ws = (char*)d_ws;
  unsigned short* Bp = (unsigned short*)ws;                       // 16 MB (hi)
  unsigned short* Ap = (unsigned short*)(ws + 16777216);          // 512 KB (hi)
  float* left = (float*)(ws + 17301504);                          // 8 KB
  float* right = (float*)(ws + 17309696);                         // 256 KB
  float* minbuf = (float*)(ws + 17571840);                        // 16 MB

  pack_sumsq_kernel<<<((kB + kN) * 64 + 255) / 256, 256, 0, stream>>>(
      x, train, features, Ap, Bp, left, right);
  knn_main_kernel<<<dim3(32, 16), 256, 0, stream>>>(Ap, Bp, left, right, minbuf);
  select_rescore_kernel<<<kB / 4, 256, 0, stream>>>(
      x, train, features, left, right, labels, minbuf, out);
}

// Round 10
// 284.464 us; speedup vs baseline: 1.0776x; 1.0776x over previous
//
#include <hip/hip_runtime.h>
#include <hip/hip_bf16.h>
#include <cstdint>
#include <cstddef>

typedef short bf16x8 __attribute__((ext_vector_type(8)));
typedef float f32x4 __attribute__((ext_vector_type(4)));

namespace {
constexpr int kB = 2048;
constexpr int kN = 65536;
constexpr int kF = 128;
constexpr int kLabels = 10;
constexpr int kIMax = 0x7fffffff;

constexpr int BCOLS = 128;          // cols per WG (owned for whole kernel)
constexpr int PROWS = 128;          // rows per panel
constexpr int NPANEL = kB / PROWS;  // 16 panels (all rows per WG)
constexpr int NCH = 4;              // K chunks of 32 (hi-only bf16 ranking)
constexpr int NG = NPANEL * NCH;    // 64 chunk-iterations per WG
constexpr int NSUB = kN / 16;       // 4096 bins of 16 strided cols
// hi-only bf16 ranking: sigma_d ~= 0.012; margin 0.25 ~= 20 sigma (needs >= 8).
// Rescore is exact fp32; margin only widens the rescored set slightly.
constexpr float kMargin = 0.25f;
}

#define TOP3_INSERT(dd, ii, D0, I0, D1, I1, D2, I2)                              \
  do {                                                                           \
    float _d = (dd); int _i = (ii);                                              \
    if (_d < (D0) || (_d == (D0) && _i < (I0))) {                                \
      (D2) = (D1); (I2) = (I1); (D1) = (D0); (I1) = (I0); (D0) = _d; (I0) = _i;  \
    } else if (_d < (D1) || (_d == (D1) && _i < (I1))) {                         \
      (D2) = (D1); (I2) = (I1); (D1) = _d; (I1) = _i;                            \
    } else if (_d < (D2) || (_d == (D2) && _i < (I2))) {                         \
      (D2) = _d; (I2) = _i;                                                      \
    }                                                                            \
  } while (0)

__device__ inline unsigned short f2bf(float a) {
  __hip_bfloat16 h = __float2bfloat16(a);
  return __builtin_bit_cast(unsigned short, h);
}

__device__ inline void gload_lds16(const void* g, void* l) {
  __builtin_amdgcn_global_load_lds(
      (const __attribute__((address_space(1))) void*)g,
      (__attribute__((address_space(3))) void*)l, 16, 0, 0);
}

// ---------- kernel 1: fused pack (bf16 hi only) + sumsq (r9 verbatim) ----------
__global__ __launch_bounds__(256) void pack_sumsq_kernel(
    const float* __restrict__ x, const float* __restrict__ train,
    const float* __restrict__ features, unsigned short* __restrict__ Ap,
    unsigned short* __restrict__ Bp, float* __restrict__ left,
    float* __restrict__ right) {
  const int wid = (int)((blockIdx.x * 256 + threadIdx.x) >> 6);
  const int lane = threadIdx.x & 63;
  if (wid >= kB + kN) return;
  const float2 fv = reinterpret_cast<const float2*>(features)[lane];
  const float* src;
  unsigned short* dst;
  float pm0, pm1, sm0, sm1;
  if (wid < kB) {
    src = x + (size_t)wid * kF;
    dst = Ap + (size_t)wid * 128;
    pm0 = fv.x; pm1 = fv.y;   // pack f*x
    sm0 = 1.0f; sm1 = 1.0f;   // left = sum x^2
  } else {
    src = train + (size_t)(wid - kB) * kF;
    dst = Bp + (size_t)(wid - kB) * 128;
    pm0 = 1.0f; pm1 = 1.0f;   // pack raw w
    sm0 = fv.x; sm1 = fv.y;   // right = sum (f*w)^2
  }
  const float2 v = reinterpret_cast<const float2*>(src)[lane];
  const float pa = v.x * pm0, pb = v.y * pm1;
  const float sa = v.x * sm0, sb = v.y * sm1;
  const unsigned short ha = f2bf(pa), hb = f2bf(pb);
  reinterpret_cast<unsigned int*>(dst)[lane] = (unsigned int)ha | ((unsigned int)hb << 16);
  float s = sa * sa + sb * sb;
  #pragma unroll
  for (int m = 1; m <= 32; m <<= 1) s += __shfl_xor(s, m);
  if (lane == 0) {
    if (wid < kB) left[wid] = s;
    else right[wid - kB] = s;
  }
}

// ---------- kernel 2: per-WG column slice, all rows; B read ONCE ----------
// grid 512 (one WG per 128-col slice, 2 WG/CU). 256 thr (4 waves: 2m x 2n).
// B slice staged once into 32 KB LDS; A streams per (panel,chunk) with 3-deep
// counted-vmcnt pipeline (A is 512 KB total -> permanently L2-resident).
__global__ __launch_bounds__(256, 2) void knn_main_kernel(
    const unsigned short* __restrict__ Ap, const unsigned short* __restrict__ Bp,
    const float* __restrict__ left, const float* __restrict__ right,
    float* __restrict__ minbuf) {
  __shared__ alignas(16) unsigned short lsB[NCH * BCOLS * 32];  // 32 KB [c][col][4 slots]
  __shared__ alignas(16) unsigned short lsA[3][PROWS * 32];     // 24 KB
  __shared__ float lsL[kB];                                      // 8 KB (all left)
  __shared__ float lsR[BCOLS];                                   // 512 B

  const int slice = blockIdx.x;
  const int col0 = slice * BCOLS;
  const int t = threadIdx.x;
  const int lane = t & 63;
  const int wm = (t >> 6) >> 1;  // 0..1
  const int wn = (t >> 6) & 1;   // 0..1

  // stage left (all rows) + right (this slice) into LDS
  #pragma unroll
  for (int i = 0; i < 2; ++i)
    reinterpret_cast<float4*>(lsL)[t + i * 256] =
        reinterpret_cast<const float4*>(left)[t + i * 256];
  if (t < BCOLS / 4)
    reinterpret_cast<float4*>(lsR)[t] =
        reinterpret_cast<const float4*>(right + col0)[t];

  // staging address precompute (verified swizzle family): instr i covers
  // row/col i*64 + t/4, slot p = t&3 -> global slot p ^ ((r>>1)&3).
  const int rr = t >> 2;
  const int p = t & 3;
  size_t aoff[2], boff[2];
  int ldsoff[2];
  #pragma unroll
  for (int i = 0; i < 2; ++i) {
    const int r = i * 64 + rr;
    const int ps = p ^ ((r >> 1) & 3);
    aoff[i] = (size_t)r * 256 + (size_t)ps * 16;             // + mp*32768 + c*64
    boff[i] = (size_t)(col0 + r) * 256 + (size_t)ps * 16;    // + c*64
    ldsoff[i] = i * 4096 + t * 16;
  }

  // fragment LDS byte offsets (swizzled reads, verified r2-r9)
  int offA[2], offB[4];
  #pragma unroll
  for (int mf = 0; mf < 4; ++mf) {
    if (mf < 2) {}
  }
  int offAf[4], offBf[4];
  #pragma unroll
  for (int mf = 0; mf < 4; ++mf) {
    const int rl = wm * 64 + mf * 16 + (lane & 15);
    offAf[mf] = rl * 64 + (((lane >> 4) ^ ((rl >> 1) & 3)) * 16);
  }
  #pragma unroll
  for (int nf = 0; nf < 4; ++nf) {
    const int cl = wn * 64 + nf * 16 + (lane & 15);
    offBf[nf] = cl * 64 + (((lane >> 4) ^ ((cl >> 1) & 3)) * 16);
  }

  const char* ApB = (const char*)Ap;
  const char* BpB = (const char*)Bp;

  auto stageA = [&](int buf, int g) {
    const int mp = g >> 2, c = g & 3;
    char* lA = (char*)&lsA[buf][0];
    #pragma unroll
    for (int i = 0; i < 2; ++i)
      gload_lds16(ApB + aoff[i] + (size_t)mp * 32768 + (size_t)c * 64,
                  lA + ldsoff[i]);
  };

  // prologue: stage ALL of B (4 chunks x 2 instr) + A chunks 0,1
  {
    char* lB = (char*)&lsB[0];
    #pragma unroll
    for (int c = 0; c < NCH; ++c)
      #pragma unroll
      for (int i = 0; i < 2; ++i)
        gload_lds16(BpB + boff[i] + (size_t)c * 64, lB + c * 8192 + ldsoff[i]);
  }
  stageA(0, 0);
  stageA(1, 1);
  __syncthreads();  // full drain: B + A0 + A1 + lsL/lsR visible

  // hoisted: right values for this lane's 4 col-fragments (WG-fixed cols)
  float rj[4];
  #pragma unroll
  for (int nf = 0; nf < 4; ++nf)
    rj[nf] = lsR[wn * 64 + nf * 16 + (lane & 15)];

  const bool bwriter = (lane & 3) == 0;
  const int subbase = slice * 8 + wn * 4 + ((lane >> 2) & 3);

  for (int mp = 0; mp < NPANEL; ++mp) {
    f32x4 acc[4][4];
    #pragma unroll
    for (int mf = 0; mf < 4; ++mf)
      #pragma unroll
      for (int nf = 0; nf < 4; ++nf)
        acc[mf][nf] = (f32x4){0.f, 0.f, 0.f, 0.f};

    for (int c = 0; c < NCH; ++c) {
      const int g = mp * 4 + c;
      if (g < NG - 2) stageA((g + 2) % 3, g + 2);
      // counted wait: stage g ready iff <= 2 newer A-stages (2 loads each) out.
      if (g < NG - 2)       asm volatile("s_waitcnt vmcnt(4)" ::: "memory");
      else if (g == NG - 2) asm volatile("s_waitcnt vmcnt(2)" ::: "memory");
      else                  asm volatile("s_waitcnt vmcnt(0)" ::: "memory");
      __builtin_amdgcn_s_barrier();
      asm volatile("" ::: "memory");

      const char* lA = (const char*)&lsA[g % 3][0];
      const char* lB = (const char*)&lsB[c * 4096 * 2 / 2];  // c*8192 bytes
      lB = (const char*)&lsB[0] + c * 8192;
      bf16x8 a[4], b[4];
      #pragma unroll
      for (int mf = 0; mf < 4; ++mf)
        a[mf] = *reinterpret_cast<const bf16x8*>(lA + offAf[mf]);
      #pragma unroll
      for (int nf = 0; nf < 4; ++nf)
        b[nf] = *reinterpret_cast<const bf16x8*>(lB + offBf[nf]);
      __builtin_amdgcn_s_setprio(1);
      #pragma unroll
      for (int mf = 0; mf < 4; ++mf)
        #pragma unroll
        for (int nf = 0; nf < 4; ++nf)
          acc[mf][nf] = __builtin_amdgcn_mfma_f32_16x16x32_bf16(
              a[mf], b[nf], acc[mf][nf], 0, 0, 0);
      __builtin_amdgcn_s_setprio(0);
      asm volatile("" ::: "memory");
      __builtin_amdgcn_s_barrier();   // reads of A buf g done before overwrite
      asm volatile("" ::: "memory");
    }

    // panel epilogue: distance estimate + per-bin (16 strided cols) min.
    // bin = { wn*64 + nf*16 + bq*4 + g : nf 0..3, g 0..3 }, bq = (lane>>2)&3.
    const int prow0 = mp * PROWS + wm * 64;
    #pragma unroll
    for (int mf = 0; mf < 4; ++mf) {
      #pragma unroll
      for (int rg = 0; rg < 4; ++rg) {
        const int row = prow0 + mf * 16 + (lane >> 4) * 4 + rg;
        const float l = lsL[row];
        float d0 = sqrtf(l + rj[0]) - 2.0f * acc[mf][0][rg];
        float d1 = sqrtf(l + rj[1]) - 2.0f * acc[mf][1][rg];
        float d2 = sqrtf(l + rj[2]) - 2.0f * acc[mf][2][rg];
        float d3 = sqrtf(l + rj[3]) - 2.0f * acc[mf][3][rg];
        float v = fminf(fminf(d0, d1), fminf(d2, d3));
        v = fminf(v, __shfl_xor(v, 1));
        v = fminf(v, __shfl_xor(v, 2));
        if (bwriter)
          minbuf[(size_t)row * NSUB + subbase] = v;
      }
    }
  }
}

// ---------- kernel 3: select bins, exact fp32 rescore, outputs ----------
__global__ __launch_bounds__(256) void select_rescore_kernel(
    const float* __restrict__ x, const float* __restrict__ train,
    const float* __restrict__ features, const float* __restrict__ left,
    const float* __restrict__ right, const int* __restrict__ labels,
    const float* __restrict__ minbuf, float* __restrict__ out) {
  __shared__ float Xs[4][kF];
  const int t = threadIdx.x;
  if (t < 128) {
    const int rr = t >> 5, q = t & 31;
    float4 xv = reinterpret_cast<const float4*>(
        x + (size_t)(blockIdx.x * 4 + rr) * kF)[q];
    const float4 f = reinterpret_cast<const float4*>(features)[q];
    xv.x *= f.x; xv.y *= f.y; xv.z *= f.z; xv.w *= f.w;
    reinterpret_cast<float4*>(&Xs[rr][0])[q] = xv;
  }
  __syncthreads();
  const int wave = t >> 6, lane = t & 63;
  const int row = blockIdx.x * 4 + wave;
  const float lr = left[row];
  const float* mrow = minbuf + (size_t)row * NSUB;

  // pass 1: 3rd-smallest bin min
  float v0 = __builtin_inff(), v1 = v0, v2 = v0;
  #pragma unroll 4
  for (int i = 0; i < NSUB / 64; ++i) {
    const float m = mrow[i * 64 + lane];
    if (m < v0) { v2 = v1; v1 = v0; v0 = m; }
    else if (m < v1) { v2 = v1; v1 = m; }
    else if (m < v2) { v2 = m; }
  }
  #pragma unroll
  for (int msk = 1; msk <= 32; msk <<= 1) {
    const float e0 = __shfl_xor(v0, msk), e1 = __shfl_xor(v1, msk), e2 = __shfl_xor(v2, msk);
    if (e0 < v0) { v2 = v1; v1 = v0; v0 = e0; } else if (e0 < v1) { v2 = v1; v1 = e0; } else if (e0 < v2) v2 = e0;
    if (e1 < v0) { v2 = v1; v1 = v0; v0 = e1; } else if (e1 < v1) { v2 = v1; v1 = e1; } else if (e1 < v2) v2 = e1;
    if (e2 < v0) { v2 = v1; v1 = v0; v0 = e2; } else if (e2 < v1) { v2 = v1; v1 = e2; } else if (e2 < v2) v2 = e2;
  }
  const float tau = v2 + kMargin;

  // pass 2: exact fp32 rescore of selected bins.
  // bin sub -> j = (sub>>3)*128 + ((sub>>2)&1)*64 + nf*16 + (sub&3)*4 + g,
  // nf = lane>>2 (0..3), g = lane&3, lanes 0..15 active.
  float d0 = __builtin_inff(), d1 = d0, d2 = d0;
  int i0 = kIMax, i1 = kIMax, i2 = kIMax;
  for (int base = 0; base < NSUB; base += 64) {
    const float m = mrow[base + lane];
    unsigned long long msk = __ballot(m <= tau);
    while (msk) {
      const int bpos = __builtin_ctzll(msk);
      msk &= msk - 1;
      const int sub = base + bpos;
      if (lane < 16) {
        const int j = (sub >> 3) * 128 + ((sub >> 2) & 1) * 64 +
                      (lane >> 2) * 16 + (sub & 3) * 4 + (lane & 3);
        const float4* wp = reinterpret_cast<const float4*>(train + (size_t)j * kF);
        float acc = 0.f;
        #pragma unroll 8
        for (int kq = 0; kq < 32; ++kq) {
          const float4 w4 = wp[kq];
          const float4 x4 = reinterpret_cast<const float4*>(&Xs[wave][0])[kq];
          acc = fmaf(x4.w, w4.w, fmaf(x4.z, w4.z, fmaf(x4.y, w4.y, fmaf(x4.x, w4.x, acc))));
        }
        const float d = sqrtf(lr + right[j]) - 2.0f * acc;
        TOP3_INSERT(d, j, d0, i0, d1, i1, d2, i2);
      }
    }
  }
  #pragma unroll
  for (int msk = 1; msk <= 32; msk <<= 1) {
    const float e0 = __shfl_xor(d0, msk), e1 = __shfl_xor(d1, msk), e2 = __shfl_xor(d2, msk);
    const int f0 = __shfl_xor(i0, msk), f1 = __shfl_xor(i1, msk), f2 = __shfl_xor(i2, msk);
    TOP3_INSERT(e0, f0, d0, i0, d1, i1, d2, i2);
    TOP3_INSERT(e1, f1, d0, i0, d1, i1, d2, i2);
    TOP3_INSERT(e2, f2, d0, i0, d1, i1, d2, i2);
  }
  if (lane == 0) {
    const int l0 = labels[i0], l1 = labels[i1], l2 = labels[i2];
    const int o = (l0 + l1 + l2) / 3;
    float* one_hot = out;
    float* values = out + (size_t)kB * kLabels;
    float* indices = values + (size_t)kB * 3;
    float* labs = indices + (size_t)kB * 3;
    #pragma unroll
    for (int c = 0; c < kLabels; ++c)
      one_hot[(size_t)row * kLabels + c] = (c == o) ? 1.0f : 0.0f;
    values[row * 3 + 0] = -d0; values[row * 3 + 1] = -d1; values[row * 3 + 2] = -d2;
    indices[row * 3 + 0] = (float)i0; indices[row * 3 + 1] = (float)i1; indices[row * 3 + 2] = (float)i2;
    labs[row * 3 + 0] = (float)l0; labs[row * 3 + 1] = (float)l1; labs[row * 3 + 2] = (float)l2;
  }
}

extern "C" void kernel_launch(void* const* d_in, const int* in_sizes, int n_in,
                              void* d_out, int out_size, void* d_ws, size_t ws_size,
                              hipStream_t stream) {
  const float* x = (const float*)d_in[0];
  const float* train = (const float*)d_in[1];
  const int* labels = (const int*)d_in[2];
  const float* features = (const float*)d_in[3];
  float* out = (float*)d_out;

  char* ws = (char*)d_ws;
  unsigned short* Bp = (unsigned short*)ws;                       // 16 MB (hi)
  unsigned short* Ap = (unsigned short*)(ws + 16777216);          // 512 KB (hi)
  float* left = (float*)(ws + 17301504);                          // 8 KB
  float* right = (float*)(ws + 17309696);                         // 256 KB
  float* minbuf = (float*)(ws + 17571840);                        // 32 MB

  pack_sumsq_kernel<<<((kB + kN) * 64 + 255) / 256, 256, 0, stream>>>(
      x, train, features, Ap, Bp, left, right);
  knn_main_kernel<<<kN / BCOLS, 256, 0, stream>>>(Ap, Bp, left, right, minbuf);
  select_rescore_kernel<<<kB / 4, 256, 0, stream>>>(
      x, train, features, left, right, labels, minbuf, out);
}